// Round 2
// baseline (139.650 us; speedup 1.0000x reference)
//
#include <hip/hip_runtime.h>
#include <hip/hip_bf16.h>

#define NN   768
#define INP  256
#define NH   4
#define FH   64
#define DOUT 256   // NH*FH

__device__ __forceinline__ float b2f(unsigned short u) {
    union { unsigned int i; float f; } v;
    v.i = ((unsigned int)u) << 16;
    return v.f;
}
__device__ __forceinline__ unsigned short f2b(float f) {
    union { float f; unsigned int i; } v; v.f = f;
    // round-to-nearest-even bf16
    unsigned int lsb = (v.i >> 16) & 1;
    v.i += 0x7FFFu + lsb;
    return (unsigned short)(v.i >> 16);
}

// ---------------------------------------------------------------------------
// Kernel 0a: dtype detection. If x is packed bf16 of ~N(0,1) data, the LOW
// ushort of each u32 word is itself a bf16 with exponent field in [124,127]
// w.p. ~0.90. If x is f32, those bits are low mantissa bits (uniform) -> ~1.6%.
// flag = 1 (bf16) / 0 (f32).
// ---------------------------------------------------------------------------
__global__ void detect_kernel(const unsigned int* __restrict__ xw,
                              int* __restrict__ flag) {
    const int lane = threadIdx.x;            // 64 threads
    unsigned int u = xw[lane * 7];
    unsigned int e = (u >> 7) & 0xFFu;       // exp field of low half as bf16
    int hit = (e >= 124u && e <= 127u) ? 1 : 0;
    #pragma unroll
    for (int d = 1; d < 64; d <<= 1) hit += __shfl_xor(hit, d);
    if (lane == 0) *flag = (hit >= 32) ? 1 : 0;
}

// ---------------------------------------------------------------------------
// Kernel 0b: canonicalize x, W, a to bf16 in workspace (copy or downcast).
// ---------------------------------------------------------------------------
__global__ __launch_bounds__(256) void convert_kernel(
    const void* __restrict__ xin, const void* __restrict__ Win,
    const void* __restrict__ ain,
    unsigned short* __restrict__ xc, unsigned short* __restrict__ Wc,
    unsigned short* __restrict__ ac, const int* __restrict__ flag)
{
    const int isbf = *flag;
    const int total = NN * INP + DOUT * INP + FH;   // 262208
    for (int idx = blockIdx.x * 256 + threadIdx.x; idx < total;
         idx += gridDim.x * 256) {
        const void* src; unsigned short* dst; int off;
        if (idx < NN * INP)               { src = xin; dst = xc; off = idx; }
        else if (idx < NN * INP + DOUT * INP)
                                          { src = Win; dst = Wc; off = idx - NN * INP; }
        else                              { src = ain; dst = ac; off = idx - NN * INP - DOUT * INP; }
        if (isbf) dst[off] = ((const unsigned short*)src)[off];
        else      dst[off] = f2b(((const float*)src)[off]);
    }
}

// ---------------------------------------------------------------------------
// Kernel 1: Wx = x @ W^T (bf16) + lin[n][h] = 0.6*sum_f a[f]*Wx[n,h,f]
// ---------------------------------------------------------------------------
__global__ __launch_bounds__(256) void wx_kernel(
    const unsigned short* __restrict__ x,
    const unsigned short* __restrict__ W,
    const unsigned short* __restrict__ a,
    unsigned short* __restrict__ Wxh,
    float* __restrict__ lin)
{
    __shared__ float xs[4][INP];
    const int tid = threadIdx.x;
    const int r0  = blockIdx.x * 4;

    for (int idx = tid; idx < 4 * INP; idx += 256)
        xs[idx >> 8][idx & 255] = b2f(x[r0 * INP + idx]);
    __syncthreads();

    const int o = tid;
    const unsigned short* wr = W + o * INP;
    float acc0 = 0.f, acc1 = 0.f, acc2 = 0.f, acc3 = 0.f;
    #pragma unroll 4
    for (int k = 0; k < INP; k += 4) {
        ushort4 u = *(const ushort4*)(wr + k);
        float w0 = b2f(u.x), w1 = b2f(u.y), w2 = b2f(u.z), w3 = b2f(u.w);
        acc0 += xs[0][k] * w0 + xs[0][k + 1] * w1 + xs[0][k + 2] * w2 + xs[0][k + 3] * w3;
        acc1 += xs[1][k] * w0 + xs[1][k + 1] * w1 + xs[1][k + 2] * w2 + xs[1][k + 3] * w3;
        acc2 += xs[2][k] * w0 + xs[2][k + 1] * w1 + xs[2][k + 2] * w2 + xs[2][k + 3] * w3;
        acc3 += xs[3][k] * w0 + xs[3][k + 1] * w1 + xs[3][k + 2] * w2 + xs[3][k + 3] * w3;
    }

    Wxh[(r0 + 0) * DOUT + o] = f2b(acc0);
    Wxh[(r0 + 1) * DOUT + o] = f2b(acc1);
    Wxh[(r0 + 2) * DOUT + o] = f2b(acc2);
    Wxh[(r0 + 3) * DOUT + o] = f2b(acc3);

    const int f = tid & 63;
    const int h = tid >> 6;
    const float af = 0.6f * b2f(a[f]);
    float v0 = af * acc0, v1 = af * acc1, v2 = af * acc2, v3 = af * acc3;
    #pragma unroll
    for (int d = 1; d < 64; d <<= 1) {
        v0 += __shfl_xor(v0, d);
        v1 += __shfl_xor(v1, d);
        v2 += __shfl_xor(v2, d);
        v3 += __shfl_xor(v3, d);
    }
    if (f == 0) {
        lin[(r0 + 0) * NH + h] = v0;
        lin[(r0 + 1) * NH + h] = v1;
        lin[(r0 + 2) * NH + h] = v2;
        lin[(r0 + 3) * NH + h] = v3;
    }
}

// ---------------------------------------------------------------------------
// Kernel 2: per-node attention. One block per node i.
// ---------------------------------------------------------------------------
__global__ __launch_bounds__(256) void attn_kernel(
    const unsigned short* __restrict__ Wxh,
    const float* __restrict__ lin,
    const int* __restrict__ adj,
    const unsigned short* __restrict__ aa,
    void* __restrict__ outv,
    const int* __restrict__ flag)
{
    __shared__ float att[NH][NN];   // 12 KB

    const int i    = blockIdx.x;
    const int tid  = threadIdx.x;
    const int wv   = tid >> 6;
    const int lane = tid & 63;
    const int jq   = lane >> 4;   // 0..3
    const int fg   = lane & 15;   // 0..15
    const int isbf = *flag;

    float4 wi[NH];
    #pragma unroll
    for (int h = 0; h < NH; ++h) {
        ushort4 u = *(const ushort4*)(Wxh + i * DOUT + h * FH + fg * 4);
        wi[h] = make_float4(b2f(u.x), b2f(u.y), b2f(u.z), b2f(u.w));
    }
    float4 a4;
    {
        ushort4 u = *(const ushort4*)(aa + fg * 4);
        a4 = make_float4(0.4f * b2f(u.x), 0.4f * b2f(u.y),
                         0.4f * b2f(u.z), 0.4f * b2f(u.w));
    }
    float lini[NH];
    #pragma unroll
    for (int h = 0; h < NH; ++h) lini[h] = lin[i * NH + h];

    const int* adjrow = adj + i * NN;

    // ---- e-phase ----
    for (int q = wv; q < NN / 4; q += 4) {
        const int j  = q * 4 + jq;
        const int aj = adjrow[j];
        const unsigned short* wjp = Wxh + j * DOUT + fg * 4;
        float e[NH];
        #pragma unroll
        for (int h = 0; h < NH; ++h) {
            ushort4 u = *(const ushort4*)(wjp + h * FH);
            float x0 = wi[h].x + b2f(u.x);
            float x1 = wi[h].y + b2f(u.y);
            float x2 = wi[h].z + b2f(u.z);
            float x3 = wi[h].w + b2f(u.w);
            float s = a4.x * fabsf(x0) + a4.y * fabsf(x1)
                    + a4.z * fabsf(x2) + a4.w * fabsf(x3);
            s += __shfl_xor(s, 1);
            s += __shfl_xor(s, 2);
            s += __shfl_xor(s, 4);
            s += __shfl_xor(s, 8);
            e[h] = s;
        }
        if (fg == 0) {
            const float4 lj = *(const float4*)(lin + j * NH);
            att[0][j] = aj ? (lini[0] + lj.x + e[0]) : -__builtin_inff();
            att[1][j] = aj ? (lini[1] + lj.y + e[1]) : -__builtin_inff();
            att[2][j] = aj ? (lini[2] + lj.z + e[2]) : -__builtin_inff();
            att[3][j] = aj ? (lini[3] + lj.w + e[3]) : -__builtin_inff();
        }
    }
    __syncthreads();

    // ---- softmax: wave wv owns head h = wv ----
    {
        const int h = wv;
        float vals[12];
        float m = -__builtin_inff();
        #pragma unroll
        for (int t = 0; t < 12; ++t) {
            vals[t] = att[h][t * 64 + lane];
            m = fmaxf(m, vals[t]);
        }
        #pragma unroll
        for (int d = 1; d < 64; d <<= 1) m = fmaxf(m, __shfl_xor(m, d));
        float s = 0.f;
        #pragma unroll
        for (int t = 0; t < 12; ++t) {
            vals[t] = __expf(vals[t] - m);
            s += vals[t];
        }
        #pragma unroll
        for (int d = 1; d < 64; d <<= 1) s += __shfl_xor(s, d);
        const float inv = 1.f / s;
        #pragma unroll
        for (int t = 0; t < 12; ++t) att[h][t * 64 + lane] = vals[t] * inv;
    }
    __syncthreads();

    // ---- output ----
    {
        const int h = wv;
        const int f = lane;
        const unsigned short* col = Wxh + h * FH + f;
        float acc = 0.f;
        #pragma unroll 4
        for (int j0 = 0; j0 < NN; j0 += 4) {
            const float4 at = *(const float4*)&att[h][j0];
            acc += at.x * b2f(col[(j0 + 0) * DOUT]);
            acc += at.y * b2f(col[(j0 + 1) * DOUT]);
            acc += at.z * b2f(col[(j0 + 2) * DOUT]);
            acc += at.w * b2f(col[(j0 + 3) * DOUT]);
        }
        if (isbf) ((unsigned short*)outv)[i * DOUT + tid] = f2b(acc);
        else      ((float*)outv)[i * DOUT + tid] = acc;
    }
}

extern "C" void kernel_launch(void* const* d_in, const int* in_sizes, int n_in,
                              void* d_out, int out_size, void* d_ws, size_t ws_size,
                              hipStream_t stream) {
    // identify inputs by element count (all distinct); fall back to dict order
    const void* px = d_in[0]; const void* padj = d_in[1];
    const void* pW = d_in[2]; const void* pa  = d_in[3];
    for (int t = 0; t < n_in; ++t) {
        switch (in_sizes[t]) {
            case NN * INP:   px   = d_in[t]; break;   // 196608
            case NN * NN:    padj = d_in[t]; break;   // 589824
            case DOUT * INP: pW   = d_in[t]; break;   // 65536
            case FH:         pa   = d_in[t]; break;   // 64
        }
    }

    char* ws = (char*)d_ws;
    int*            flag = (int*)ws;                                  // 512 B
    unsigned short* xc   = (unsigned short*)(ws + 512);               // 393216 B
    unsigned short* Wc   = (unsigned short*)(ws + 512 + 393216);      // 131072 B
    unsigned short* ac   = (unsigned short*)(ws + 512 + 393216 + 131072);          // 512 B
    unsigned short* Wxh  = (unsigned short*)(ws + 512 + 393216 + 131072 + 512);    // 393216 B
    float*          lin  = (float*)(ws + 512 + 393216 + 131072 + 512 + 393216);    // 12288 B

    detect_kernel<<<1, 64, 0, stream>>>((const unsigned int*)px, flag);
    convert_kernel<<<512, 256, 0, stream>>>(px, pW, pa, xc, Wc, ac, flag);
    wx_kernel<<<NN / 4, 256, 0, stream>>>(xc, Wc, ac, Wxh, lin);
    attn_kernel<<<NN, 256, 0, stream>>>(Wxh, lin, (const int*)padj, ac, d_out, flag);
}

// Round 3
// 108.100 us; speedup vs baseline: 1.2919x; 1.2919x over previous
//
#include <hip/hip_runtime.h>
#include <hip/hip_bf16.h>

#define NN   768
#define INP  256
#define NH   4
#define FH   64
#define DOUT 256   // NH*FH

__device__ __forceinline__ float b2f(unsigned short u) {
    union { unsigned int i; float f; } v;
    v.i = ((unsigned int)u) << 16;
    return v.f;
}
__device__ __forceinline__ unsigned short f2b(float f) {
    union { float f; unsigned int i; } v; v.f = f;
    unsigned int lsb = (v.i >> 16) & 1;
    v.i += 0x7FFFu + lsb;
    return (unsigned short)(v.i >> 16);
}

// Per-wave dtype detect: if x is packed bf16 of ~N(0,1), the LOW ushort of a
// u32 word is a bf16 with exp field in [124,127] w.p. ~0.86; if x is f32 those
// are mantissa bits (~1.6%). 64 samples, majority vote. (Round 2 confirmed f32.)
__device__ __forceinline__ int detect_bf16(const void* xin) {
    const unsigned int* xw = (const unsigned int*)xin;
    unsigned int u = xw[(threadIdx.x & 63) * 7];
    unsigned int e = (u >> 7) & 0xFFu;
    unsigned long long m = __ballot(e >= 124u && e <= 127u);
    return (__popcll(m) >= 32) ? 1 : 0;
}

// ---------------------------------------------------------------------------
// Kernel 1: Wx = x @ W^T  -> bf16 Wxh;  lin[n][h] = 0.6*sum_f a[f]*Wx[n,h,f];
// also publishes flag + f32 copy of a. Reads x/W/a in native dtype (detected).
// 192 blocks x 256 thr, 4 nodes per block, thread o = output col (h*64+f).
// ---------------------------------------------------------------------------
__global__ __launch_bounds__(256) void wx_kernel(
    const void* __restrict__ xin, const void* __restrict__ Win,
    const void* __restrict__ ain,
    unsigned short* __restrict__ Wxh, float* __restrict__ lin,
    float* __restrict__ af32, int* __restrict__ flagout)
{
    const int isbf = detect_bf16(xin);
    __shared__ float xs[4][INP];
    const int tid = threadIdx.x;
    const int r0  = blockIdx.x * 4;

    if (isbf) {
        const unsigned short* xp = (const unsigned short*)xin + r0 * INP;
        for (int idx = tid; idx < 4 * INP; idx += 256)
            xs[idx >> 8][idx & 255] = b2f(xp[idx]);
    } else {
        const float* xp = (const float*)xin + r0 * INP;
        for (int idx = tid; idx < 4 * INP; idx += 256)
            xs[idx >> 8][idx & 255] = xp[idx];
    }
    __syncthreads();

    const int o = tid;
    float acc0 = 0.f, acc1 = 0.f, acc2 = 0.f, acc3 = 0.f;
    if (isbf) {
        const unsigned short* wr = (const unsigned short*)Win + o * INP;
        #pragma unroll 4
        for (int k = 0; k < INP; k += 4) {
            ushort4 u = *(const ushort4*)(wr + k);
            float4 w = make_float4(b2f(u.x), b2f(u.y), b2f(u.z), b2f(u.w));
            float4 x0 = *(const float4*)&xs[0][k];
            float4 x1 = *(const float4*)&xs[1][k];
            float4 x2 = *(const float4*)&xs[2][k];
            float4 x3 = *(const float4*)&xs[3][k];
            acc0 += x0.x * w.x + x0.y * w.y + x0.z * w.z + x0.w * w.w;
            acc1 += x1.x * w.x + x1.y * w.y + x1.z * w.z + x1.w * w.w;
            acc2 += x2.x * w.x + x2.y * w.y + x2.z * w.z + x2.w * w.w;
            acc3 += x3.x * w.x + x3.y * w.y + x3.z * w.z + x3.w * w.w;
        }
    } else {
        const float* wr = (const float*)Win + o * INP;
        #pragma unroll 4
        for (int k = 0; k < INP; k += 4) {
            float4 w = *(const float4*)(wr + k);
            float4 x0 = *(const float4*)&xs[0][k];
            float4 x1 = *(const float4*)&xs[1][k];
            float4 x2 = *(const float4*)&xs[2][k];
            float4 x3 = *(const float4*)&xs[3][k];
            acc0 += x0.x * w.x + x0.y * w.y + x0.z * w.z + x0.w * w.w;
            acc1 += x1.x * w.x + x1.y * w.y + x1.z * w.z + x1.w * w.w;
            acc2 += x2.x * w.x + x2.y * w.y + x2.z * w.z + x2.w * w.w;
            acc3 += x3.x * w.x + x3.y * w.y + x3.z * w.z + x3.w * w.w;
        }
    }

    Wxh[(r0 + 0) * DOUT + o] = f2b(acc0);
    Wxh[(r0 + 1) * DOUT + o] = f2b(acc1);
    Wxh[(r0 + 2) * DOUT + o] = f2b(acc2);
    Wxh[(r0 + 3) * DOUT + o] = f2b(acc3);

    const int f = tid & 63;
    const int h = tid >> 6;
    const float av = isbf ? b2f(((const unsigned short*)ain)[f])
                          : ((const float*)ain)[f];
    if (blockIdx.x == 0) {
        if (tid < 64) af32[tid] = av;
        if (tid == 0) *flagout = isbf;
    }

    const float af = 0.6f * av;
    float v0 = af * acc0, v1 = af * acc1, v2 = af * acc2, v3 = af * acc3;
    #pragma unroll
    for (int d = 1; d < 64; d <<= 1) {
        v0 += __shfl_xor(v0, d);
        v1 += __shfl_xor(v1, d);
        v2 += __shfl_xor(v2, d);
        v3 += __shfl_xor(v3, d);
    }
    if (f == 0) {
        lin[(r0 + 0) * NH + h] = v0;
        lin[(r0 + 1) * NH + h] = v1;
        lin[(r0 + 2) * NH + h] = v2;
        lin[(r0 + 3) * NH + h] = v3;
    }
}

// ---------------------------------------------------------------------------
// Kernel 2: per-node attention with neighbor COMPACTION (~50% of j are masked).
// Phase A: ballot-compact active j into jlist (order irrelevant for the sums).
// Phase B: e over active slots; lanes = 4 slots x 16 f-groups, shuffle-reduce.
// Phase C: softmax max+expsum per head-wave; normalization deferred to epilogue.
// Phase D: out[i,h*64+f] = inv * sum_s att[h][s] * Wx[jlist[s],h,f].
// ---------------------------------------------------------------------------
__global__ __launch_bounds__(256) void attn_kernel(
    const unsigned short* __restrict__ Wxh,
    const float* __restrict__ lin,
    const int* __restrict__ adj,
    const float* __restrict__ af32,
    void* __restrict__ outv,
    const int* __restrict__ flag)
{
    __shared__ float att[NH][NN];            // 12 KB (slot-indexed exp values)
    __shared__ unsigned short jlist[NN];     // 1.5 KB
    __shared__ int cnt;

    const int i    = blockIdx.x;
    const int tid  = threadIdx.x;
    const int wv   = tid >> 6;
    const int lane = tid & 63;
    const int jq   = lane >> 4;
    const int fg   = lane & 15;
    const int isbf = *flag;

    if (tid == 0) cnt = 0;

    float4 wi[NH];
    #pragma unroll
    for (int h = 0; h < NH; ++h) {
        ushort4 u = *(const ushort4*)(Wxh + i * DOUT + h * FH + fg * 4);
        wi[h] = make_float4(b2f(u.x), b2f(u.y), b2f(u.z), b2f(u.w));
    }
    float4 a4;
    {
        const float4 av = *(const float4*)(af32 + fg * 4);
        a4 = make_float4(0.4f * av.x, 0.4f * av.y, 0.4f * av.z, 0.4f * av.w);
    }
    float lini[NH];
    #pragma unroll
    for (int h = 0; h < NH; ++h) lini[h] = lin[i * NH + h];

    __syncthreads();   // cnt initialized

    // ---- Phase A: compaction ----
    const int* adjrow = adj + i * NN;
    #pragma unroll
    for (int t = 0; t < 3; ++t) {
        const int j = wv * 192 + t * 64 + lane;
        const bool act = adjrow[j] != 0;
        const unsigned long long m = __ballot(act);
        const int pre = __popcll(m & ((1ull << lane) - 1ull));
        int base = 0;
        if (lane == 0) base = atomicAdd(&cnt, __popcll(m));
        base = __shfl(base, 0);
        if (act) jlist[base + pre] = (unsigned short)j;
    }
    __syncthreads();
    const int count = cnt;

    // ---- Phase B: e over active slots ----
    for (int base = 0; base < count; base += 16) {
        const int s = base + wv * 4 + jq;
        if (s < count) {
            const int j = jlist[s];
            const unsigned short* wjp = Wxh + j * DOUT + fg * 4;
            float ev[NH];
            #pragma unroll
            for (int h = 0; h < NH; ++h) {
                ushort4 u = *(const ushort4*)(wjp + h * FH);
                float x0 = wi[h].x + b2f(u.x);
                float x1 = wi[h].y + b2f(u.y);
                float x2 = wi[h].z + b2f(u.z);
                float x3 = wi[h].w + b2f(u.w);
                float sv = a4.x * fabsf(x0) + a4.y * fabsf(x1)
                         + a4.z * fabsf(x2) + a4.w * fabsf(x3);
                sv += __shfl_xor(sv, 1);
                sv += __shfl_xor(sv, 2);
                sv += __shfl_xor(sv, 4);
                sv += __shfl_xor(sv, 8);
                ev[h] = sv;
            }
            if (fg == 0) {
                const float4 lj = *(const float4*)(lin + j * NH);
                att[0][s] = lini[0] + lj.x + ev[0];
                att[1][s] = lini[1] + lj.y + ev[1];
                att[2][s] = lini[2] + lj.z + ev[2];
                att[3][s] = lini[3] + lj.w + ev[3];
            }
        }
    }
    __syncthreads();

    // ---- Phase C: softmax (wave wv = head h); store exp, defer 1/sum ----
    const int h = wv;
    float m = -__builtin_inff();
    for (int s = lane; s < count; s += 64) m = fmaxf(m, att[h][s]);
    #pragma unroll
    for (int d = 1; d < 64; d <<= 1) m = fmaxf(m, __shfl_xor(m, d));
    float ssum = 0.f;
    for (int s = lane; s < count; s += 64) {
        const float v = __expf(att[h][s] - m);
        att[h][s] = v;
        ssum += v;
    }
    #pragma unroll
    for (int d = 1; d < 64; d <<= 1) ssum += __shfl_xor(ssum, d);
    const float inv = (count > 0) ? 1.f / ssum : 0.f;
    __syncthreads();

    // ---- Phase D: output ----
    const unsigned short* colbase = Wxh + h * FH + lane;
    float acc = 0.f;
    int s4 = 0;
    for (; s4 + 4 <= count; s4 += 4) {
        const float4  w  = *(const float4*)&att[h][s4];
        const ushort4 jj = *(const ushort4*)&jlist[s4];
        acc += w.x * b2f(colbase[(int)jj.x * DOUT]);
        acc += w.y * b2f(colbase[(int)jj.y * DOUT]);
        acc += w.z * b2f(colbase[(int)jj.z * DOUT]);
        acc += w.w * b2f(colbase[(int)jj.w * DOUT]);
    }
    for (; s4 < count; ++s4)
        acc += att[h][s4] * b2f(colbase[(int)jlist[s4] * DOUT]);
    acc *= inv;

    if (isbf) ((unsigned short*)outv)[i * DOUT + tid] = f2b(acc);
    else      ((float*)outv)[i * DOUT + tid] = acc;
}

extern "C" void kernel_launch(void* const* d_in, const int* in_sizes, int n_in,
                              void* d_out, int out_size, void* d_ws, size_t ws_size,
                              hipStream_t stream) {
    const void* px = d_in[0]; const void* padj = d_in[1];
    const void* pW = d_in[2]; const void* pa  = d_in[3];
    for (int t = 0; t < n_in; ++t) {
        switch (in_sizes[t]) {
            case NN * INP:   px   = d_in[t]; break;   // 196608
            case NN * NN:    padj = d_in[t]; break;   // 589824
            case DOUT * INP: pW   = d_in[t]; break;   // 65536
            case FH:         pa   = d_in[t]; break;   // 64
        }
    }

    char* ws = (char*)d_ws;
    int*            flag = (int*)ws;                          // [0,256)
    float*          af32 = (float*)(ws + 256);                // [256, 512)
    unsigned short* Wxh  = (unsigned short*)(ws + 512);       // 393216 B
    float*          lin  = (float*)(ws + 512 + 393216);       // 12288 B

    wx_kernel<<<NN / 4, 256, 0, stream>>>(px, pW, pa, Wxh, lin, af32, flag);
    attn_kernel<<<NN, 256, 0, stream>>>(Wxh, lin, (const int*)padj, af32, d_out, flag);
}

// Round 5
// 98.838 us; speedup vs baseline: 1.4129x; 1.0937x over previous
//
#include <hip/hip_runtime.h>
#include <hip/hip_bf16.h>

#define NN   768
#define INP  256
#define NH   4
#define FH   64
#define DOUT 256   // NH*FH

typedef _Float16 h2 __attribute__((ext_vector_type(2)));
typedef _Float16 h8 __attribute__((ext_vector_type(8)));
typedef float    f4 __attribute__((ext_vector_type(4)));

union HU { unsigned int u; h2 h; };
union HS { _Float16 h; unsigned short s; };

__device__ __forceinline__ float b2f(unsigned short u) {
    union { unsigned int i; float f; } v;
    v.i = ((unsigned int)u) << 16;
    return v.f;
}
__device__ __forceinline__ unsigned short f2b(float f) {
    union { float f; unsigned int i; } v; v.f = f;
    unsigned int lsb = (v.i >> 16) & 1;
    v.i += 0x7FFFu + lsb;
    return (unsigned short)(v.i >> 16);
}

// packed f16 add (v_pk_add_f16)
__device__ __forceinline__ unsigned int pkadd(unsigned int a, unsigned int b) {
    HU x, y, r; x.u = a; y.u = b; r.h = x.h + y.h; return r.u;
}
// acc += a2 . |s2|  (v_dot2_f32_f16 if available; abs via bit-and)
#if defined(__has_builtin)
#if __has_builtin(__builtin_amdgcn_fdot2)
#define HAVE_FDOT2 1
#endif
#endif
__device__ __forceinline__ float dot2abs(unsigned int a, unsigned int s, float acc) {
    HU x, y; x.u = a; y.u = s & 0x7FFF7FFFu;
#ifdef HAVE_FDOT2
    return __builtin_amdgcn_fdot2(x.h, y.h, acc, false);
#else
    return acc + (float)x.h.x * (float)y.h.x + (float)x.h.y * (float)y.h.y;
#endif
}

// dtype detect (round 2 measured: inputs are f32; keep the guard — cheap)
__device__ __forceinline__ int detect_bf16(const void* xin) {
    const unsigned int* xw = (const unsigned int*)xin;
    unsigned int u = xw[(threadIdx.x & 63) * 7];
    unsigned int e = (u >> 7) & 0xFFu;
    unsigned long long m = __ballot(e >= 124u && e <= 127u);
    return (__popcll(m) >= 32) ? 1 : 0;
}

// ---------------------------------------------------------------------------
// K1: Wx = x @ W^T.  Outputs: Wxf16[n][256], BT[h*64+f][n] (f16, for MFMA B),
// lin[n][h] = 0.6*sum_f a_f Wx[n,h,f], a_pk (0.4*a packed f16 pairs), flag.
// 192 blocks x 256 thr, 4 nodes per block, thread o = output col.
// ---------------------------------------------------------------------------
__global__ __launch_bounds__(256) void wx_kernel(
    const void* __restrict__ xin, const void* __restrict__ Win,
    const void* __restrict__ ain,
    _Float16* __restrict__ Wxf, _Float16* __restrict__ BT,
    float* __restrict__ lin, unsigned int* __restrict__ apk,
    int* __restrict__ flagout)
{
    const int isbf = detect_bf16(xin);
    __shared__ float xs[4][INP];
    __shared__ float sa[64];
    const int tid = threadIdx.x;
    const int r0  = blockIdx.x * 4;

    if (isbf) {
        const unsigned short* xp = (const unsigned short*)xin + r0 * INP;
        for (int idx = tid; idx < 4 * INP; idx += 256)
            xs[idx >> 8][idx & 255] = b2f(xp[idx]);
    } else {
        const float* xp = (const float*)xin + r0 * INP;
        for (int idx = tid; idx < 4 * INP; idx += 256)
            xs[idx >> 8][idx & 255] = xp[idx];
    }
    if (tid < 64)
        sa[tid] = isbf ? b2f(((const unsigned short*)ain)[tid])
                       : ((const float*)ain)[tid];
    __syncthreads();

    const int o = tid;
    float acc0 = 0.f, acc1 = 0.f, acc2 = 0.f, acc3 = 0.f;
    if (isbf) {
        const unsigned short* wr = (const unsigned short*)Win + o * INP;
        #pragma unroll 4
        for (int k = 0; k < INP; k += 4) {
            ushort4 u = *(const ushort4*)(wr + k);
            float4 w = make_float4(b2f(u.x), b2f(u.y), b2f(u.z), b2f(u.w));
            float4 x0 = *(const float4*)&xs[0][k];
            float4 x1 = *(const float4*)&xs[1][k];
            float4 x2 = *(const float4*)&xs[2][k];
            float4 x3 = *(const float4*)&xs[3][k];
            acc0 += x0.x * w.x + x0.y * w.y + x0.z * w.z + x0.w * w.w;
            acc1 += x1.x * w.x + x1.y * w.y + x1.z * w.z + x1.w * w.w;
            acc2 += x2.x * w.x + x2.y * w.y + x2.z * w.z + x2.w * w.w;
            acc3 += x3.x * w.x + x3.y * w.y + x3.z * w.z + x3.w * w.w;
        }
    } else {
        const float* wr = (const float*)Win + o * INP;
        #pragma unroll 4
        for (int k = 0; k < INP; k += 4) {
            float4 w = *(const float4*)(wr + k);
            float4 x0 = *(const float4*)&xs[0][k];
            float4 x1 = *(const float4*)&xs[1][k];
            float4 x2 = *(const float4*)&xs[2][k];
            float4 x3 = *(const float4*)&xs[3][k];
            acc0 += x0.x * w.x + x0.y * w.y + x0.z * w.z + x0.w * w.w;
            acc1 += x1.x * w.x + x1.y * w.y + x1.z * w.z + x1.w * w.w;
            acc2 += x2.x * w.x + x2.y * w.y + x2.z * w.z + x2.w * w.w;
            acc3 += x3.x * w.x + x3.y * w.y + x3.z * w.z + x3.w * w.w;
        }
    }

    // row-major f16 Wx
    Wxf[(r0 + 0) * DOUT + o] = (_Float16)acc0;
    Wxf[(r0 + 1) * DOUT + o] = (_Float16)acc1;
    Wxf[(r0 + 2) * DOUT + o] = (_Float16)acc2;
    Wxf[(r0 + 3) * DOUT + o] = (_Float16)acc3;
    // transposed copy BT[o][node] for MFMA B-fragments (8B store, 4 nodes)
    {
        HU u0, u1;
        u0.h = h2{(_Float16)acc0, (_Float16)acc1};
        u1.h = h2{(_Float16)acc2, (_Float16)acc3};
        uint2 pv; pv.x = u0.u; pv.y = u1.u;
        *(uint2*)(BT + (size_t)o * NN + r0) = pv;
    }

    const int f = tid & 63;
    const int h = tid >> 6;
    if (blockIdx.x == 0) {
        if (tid == 0) *flagout = isbf;
        if (tid < 32) {
            HU p; p.h = h2{(_Float16)(0.4f * sa[2 * tid]),
                           (_Float16)(0.4f * sa[2 * tid + 1])};
            apk[tid] = p.u;
        }
    }

    const float af = 0.6f * sa[f];
    float v0 = af * acc0, v1 = af * acc1, v2 = af * acc2, v3 = af * acc3;
    #pragma unroll
    for (int d = 1; d < 64; d <<= 1) {
        v0 += __shfl_xor(v0, d);
        v1 += __shfl_xor(v1, d);
        v2 += __shfl_xor(v2, d);
        v3 += __shfl_xor(v3, d);
    }
    if (f == 0) {
        lin[(r0 + 0) * NH + h] = v0;
        lin[(r0 + 1) * NH + h] = v1;
        lin[(r0 + 2) * NH + h] = v2;
        lin[(r0 + 3) * NH + h] = v3;
    }
}

// ---------------------------------------------------------------------------
// K2: e[h][i][j] = lin_i + lin_j + sum_f 0.4 a_f |Wx_i + Wx_j|  (masked -> -inf)
// Block = 8 i x 64 j; grid = 96 i-tiles x 12 j-tiles = 1152 blocks.
// wave = head h; lane = j. Wx j-rows staged f16 in LDS (coalesced), held packed
// in VGPRs; Wx_i read as wave-uniform 16B global loads (VMEM, broadcast).
// Inner math: v_pk_add_f16 + abs-mask + v_dot2_f32_f16 (f32 accumulate).
// ---------------------------------------------------------------------------
#define ROWP 264   // 256 + 8 f16 pad: rows stay 16B-aligned
__global__ __launch_bounds__(256, 2) void e_kernel(
    const _Float16* __restrict__ Wxf,
    const float* __restrict__ lin,
    const unsigned int* __restrict__ apk,
    const int* __restrict__ adj,
    _Float16* __restrict__ eH)
{
    __shared__ __align__(16) unsigned short wt[64 * ROWP];

    const int b    = blockIdx.x;
    const int jt   = b % 12, it = b / 12;
    const int i0   = it * 8, j0 = jt * 64;
    const int tid  = threadIdx.x;
    const int h    = tid >> 6;
    const int lane = tid & 63;

    // stage 64 j-rows (full 256 cols, f16) into LDS, coalesced 16B chunks
    for (int t = tid; t < 64 * 32; t += 256) {
        const int row = t >> 5, c = t & 31;
        const uint4 v = *(const uint4*)(Wxf + (size_t)(j0 + row) * DOUT + c * 8);
        *(uint4*)(&wt[row * ROWP + c * 8]) = v;
    }
    __syncthreads();

    // preload this lane's j-row head-slice (64 f16 = 8 x uint4) + 0.4a packed
    uint4 wj[8], ap[8];
    #pragma unroll
    for (int c = 0; c < 8; ++c)
        wj[c] = *(const uint4*)(&wt[lane * ROWP + h * FH + c * 8]);
    #pragma unroll
    for (int c = 0; c < 8; ++c)
        ap[c] = *(const uint4*)(apk + c * 4);

    const float linj = lin[(j0 + lane) * NH + h];
    const unsigned short NEGINF = 0xFC00;

    #pragma unroll
    for (int ii = 0; ii < 8; ++ii) {
        const int i = i0 + ii;
        const float lini = lin[i * NH + h];
        const int adjv = adj[(size_t)i * NN + j0 + lane];
        float acc = 0.f;
        #pragma unroll
        for (int c = 0; c < 8; ++c) {
            const uint4 wiv = *(const uint4*)(Wxf + (size_t)i * DOUT + h * FH + c * 8);
            acc = dot2abs(ap[c].x, pkadd(wiv.x, wj[c].x), acc);
            acc = dot2abs(ap[c].y, pkadd(wiv.y, wj[c].y), acc);
            acc = dot2abs(ap[c].z, pkadd(wiv.z, wj[c].z), acc);
            acc = dot2abs(ap[c].w, pkadd(wiv.w, wj[c].w), acc);
        }
        const float ev = acc + lini + linj;
        HS hv; hv.h = (_Float16)ev;
        unsigned short st = adjv ? hv.s : NEGINF;
        ((unsigned short*)eH)[((size_t)h * NN + i) * NN + j0 + lane] = st;
    }
}

// ---------------------------------------------------------------------------
// K3: fused softmax + AV via MFMA. Block = (16 i rows, 1 head); 48x4 = 192
// blocks. Step 1: each wave loads 4 e-rows, computes max/exp/sum, writes
// exp'd att (f16) into LDS A-tile. Step 2: out = A[16x768] . B[768x64] with
// v_mfma_f32_16x16x32_f16; B-frags are coalesced 16B loads from BT.
// Step 3: divide by row-sum, store out (dtype per flag).
// ---------------------------------------------------------------------------
#define KP 776   // 768 + 8 pad
__global__ __launch_bounds__(256) void av_kernel(
    const _Float16* __restrict__ eH,
    const _Float16* __restrict__ BT,
    void* __restrict__ outv,
    const int* __restrict__ flag)
{
    __shared__ __align__(16) _Float16 P[16][KP];
    __shared__ float S[16];

    const int b    = blockIdx.x;
    const int h    = b & 3, it = b >> 2;
    const int i0   = it * 16;
    const int tid  = threadIdx.x;
    const int wv   = tid >> 6;
    const int lane = tid & 63;

    // ---- step 1: softmax rows (wave wv owns rows 4wv..4wv+3) ----
    #pragma unroll
    for (int rr = 0; rr < 4; ++rr) {
        const int row = wv * 4 + rr;
        const _Float16* er = eH + ((size_t)h * NN + i0 + row) * NN;
        float v[12];
        float m = -__builtin_inff();
        #pragma unroll
        for (int c = 0; c < 12; ++c) {
            v[c] = (float)er[c * 64 + lane];
            m = fmaxf(m, v[c]);
        }
        #pragma unroll
        for (int d = 1; d < 64; d <<= 1) m = fmaxf(m, __shfl_xor(m, d));
        if (m == -__builtin_inff()) m = 0.f;   // all-masked row: exps -> 0, not NaN
        float s = 0.f;
        #pragma unroll
        for (int c = 0; c < 12; ++c) {
            const float ev = __expf(v[c] - m);   // masked (-inf) -> 0
            s += ev;
            P[row][c * 64 + lane] = (_Float16)ev;
        }
        #pragma unroll
        for (int d = 1; d < 64; d <<= 1) s += __shfl_xor(s, d);
        if (lane == 0) S[row] = fmaxf(s, 1e-30f);
    }
    __syncthreads();

    // ---- step 2: MFMA K-loop ----
    const int mrow = lane & 15;
    const int quad = lane >> 4;
    const int n0   = wv * 16;
    f4 acc = {0.f, 0.f, 0.f, 0.f};
    const _Float16* bbase = BT + ((size_t)(h * FH + n0 + mrow)) * NN + quad * 8;
    const _Float16* abase = &P[mrow][quad * 8];
    #pragma unroll 4
    for (int k0 = 0; k0 < NN; k0 += 32) {
        const h8 af = *(const h8*)(abase + k0);
        const h8 bf = *(const h8*)(bbase + k0);
        acc = __builtin_amdgcn_mfma_f32_16x16x32_f16(af, bf, acc, 0, 0, 0);
    }

    // ---- step 3: normalize + store (C layout: col=lane&15, row=quad*4+r) ----
    const int isbf = *flag;
    #pragma unroll
    for (int r = 0; r < 4; ++r) {
        const int row = quad * 4 + r;
        const float val = acc[r] / S[row];
        const size_t oidx = (size_t)(i0 + row) * DOUT + h * FH + n0 + mrow;
        if (isbf) ((unsigned short*)outv)[oidx] = f2b(val);
        else      ((float*)outv)[oidx] = val;
    }
}

extern "C" void kernel_launch(void* const* d_in, const int* in_sizes, int n_in,
                              void* d_out, int out_size, void* d_ws, size_t ws_size,
                              hipStream_t stream) {
    const void* px = d_in[0]; const void* padj = d_in[1];
    const void* pW = d_in[2]; const void* pa  = d_in[3];
    for (int t = 0; t < n_in; ++t) {
        switch (in_sizes[t]) {
            case NN * INP:   px   = d_in[t]; break;   // 196608
            case NN * NN:    padj = d_in[t]; break;   // 589824
            case DOUT * INP: pW   = d_in[t]; break;   // 65536
            case FH:         pa   = d_in[t]; break;   // 64
        }
    }

    char* ws = (char*)d_ws;
    int*          flag = (int*)ws;                         // [0,256)
    unsigned int* apk  = (unsigned int*)(ws + 256);        // 128 B
    float*        lin  = (float*)(ws + 1024);              // 12288 B -> ends 13312
    _Float16*     Wxf  = (_Float16*)(ws + 16384);          // 393216 B -> ends 409600
    _Float16*     BT   = (_Float16*)(ws + 409600);         // 393216 B -> ends 802816
    _Float16*     eH   = (_Float16*)(ws + 802816);         // 4718592 B -> ends ~5.3 MB

    wx_kernel<<<NN / 4, 256, 0, stream>>>(px, pW, pa, Wxf, BT, lin, apk, flag);
    e_kernel<<<(NN / 8) * (NN / 64), 256, 0, stream>>>(Wxf, lin, apk,
                                                       (const int*)padj, eH);
    av_kernel<<<(NN / 16) * NH, 256, 0, stream>>>(eH, BT, d_out, flag);
}

// Round 6
// 96.998 us; speedup vs baseline: 1.4397x; 1.0190x over previous
//
#include <hip/hip_runtime.h>
#include <hip/hip_bf16.h>

#define NN   768
#define INP  256
#define NH   4
#define FH   64
#define DOUT 256   // NH*FH

typedef _Float16 h2 __attribute__((ext_vector_type(2)));
typedef _Float16 h8 __attribute__((ext_vector_type(8)));
typedef float    f4 __attribute__((ext_vector_type(4)));

union HU { unsigned int u; h2 h; };

__device__ __forceinline__ float b2f(unsigned short u) {
    union { unsigned int i; float f; } v;
    v.i = ((unsigned int)u) << 16;
    return v.f;
}
__device__ __forceinline__ unsigned short f2b(float f) {
    union { float f; unsigned int i; } v; v.f = f;
    unsigned int lsb = (v.i >> 16) & 1;
    v.i += 0x7FFFu + lsb;
    return (unsigned short)(v.i >> 16);
}

// packed f16 add (v_pk_add_f16)
__device__ __forceinline__ unsigned int pkadd(unsigned int a, unsigned int b) {
    HU x, y, r; x.u = a; y.u = b; r.h = x.h + y.h; return r.u;
}
// acc += a2 . |s2|  (v_dot2_f32_f16 if available; abs via bit-and)
#if defined(__has_builtin)
#if __has_builtin(__builtin_amdgcn_fdot2)
#define HAVE_FDOT2 1
#endif
#endif
__device__ __forceinline__ float dot2abs(unsigned int a, unsigned int s, float acc) {
    HU x, y; x.u = a; y.u = s & 0x7FFF7FFFu;
#ifdef HAVE_FDOT2
    return __builtin_amdgcn_fdot2(x.h, y.h, acc, false);
#else
    return acc + (float)x.h.x * (float)y.h.x + (float)x.h.y * (float)y.h.y;
#endif
}

// dtype detect (round 2 measured: inputs are f32; keep the guard — cheap)
__device__ __forceinline__ int detect_bf16(const void* xin) {
    const unsigned int* xw = (const unsigned int*)xin;
    unsigned int u = xw[(threadIdx.x & 63) * 7];
    unsigned int e = (u >> 7) & 0xFFu;
    unsigned long long m = __ballot(e >= 124u && e <= 127u);
    return (__popcll(m) >= 32) ? 1 : 0;
}

// ---------------------------------------------------------------------------
// K1: Wx = x @ W^T.  Outputs: Wxf16[n][256], BT[h*64+f][n] (f16, for MFMA B),
// lin[n][h] = 0.6*sum_f a_f Wx[n,h,f], a_pk (0.4*a packed f16 pairs), flag.
// 192 blocks x 256 thr, 4 nodes per block, thread o = output col.
// ---------------------------------------------------------------------------
__global__ __launch_bounds__(256) void wx_kernel(
    const void* __restrict__ xin, const void* __restrict__ Win,
    const void* __restrict__ ain,
    _Float16* __restrict__ Wxf, _Float16* __restrict__ BT,
    float* __restrict__ lin, unsigned int* __restrict__ apk,
    int* __restrict__ flagout)
{
    const int isbf = detect_bf16(xin);
    __shared__ float xs[4][INP];
    __shared__ float sa[64];
    const int tid = threadIdx.x;
    const int r0  = blockIdx.x * 4;

    if (isbf) {
        const unsigned short* xp = (const unsigned short*)xin + r0 * INP;
        for (int idx = tid; idx < 4 * INP; idx += 256)
            xs[idx >> 8][idx & 255] = b2f(xp[idx]);
    } else {
        const float* xp = (const float*)xin + r0 * INP;
        for (int idx = tid; idx < 4 * INP; idx += 256)
            xs[idx >> 8][idx & 255] = xp[idx];
    }
    if (tid < 64)
        sa[tid] = isbf ? b2f(((const unsigned short*)ain)[tid])
                       : ((const float*)ain)[tid];
    __syncthreads();

    const int o = tid;
    float acc0 = 0.f, acc1 = 0.f, acc2 = 0.f, acc3 = 0.f;
    if (isbf) {
        const unsigned short* wr = (const unsigned short*)Win + o * INP;
        #pragma unroll 4
        for (int k = 0; k < INP; k += 4) {
            ushort4 u = *(const ushort4*)(wr + k);
            float4 w = make_float4(b2f(u.x), b2f(u.y), b2f(u.z), b2f(u.w));
            float4 x0 = *(const float4*)&xs[0][k];
            float4 x1 = *(const float4*)&xs[1][k];
            float4 x2 = *(const float4*)&xs[2][k];
            float4 x3 = *(const float4*)&xs[3][k];
            acc0 += x0.x * w.x + x0.y * w.y + x0.z * w.z + x0.w * w.w;
            acc1 += x1.x * w.x + x1.y * w.y + x1.z * w.z + x1.w * w.w;
            acc2 += x2.x * w.x + x2.y * w.y + x2.z * w.z + x2.w * w.w;
            acc3 += x3.x * w.x + x3.y * w.y + x3.z * w.z + x3.w * w.w;
        }
    } else {
        const float* wr = (const float*)Win + o * INP;
        #pragma unroll 4
        for (int k = 0; k < INP; k += 4) {
            float4 w = *(const float4*)(wr + k);
            float4 x0 = *(const float4*)&xs[0][k];
            float4 x1 = *(const float4*)&xs[1][k];
            float4 x2 = *(const float4*)&xs[2][k];
            float4 x3 = *(const float4*)&xs[3][k];
            acc0 += x0.x * w.x + x0.y * w.y + x0.z * w.z + x0.w * w.w;
            acc1 += x1.x * w.x + x1.y * w.y + x1.z * w.z + x1.w * w.w;
            acc2 += x2.x * w.x + x2.y * w.y + x2.z * w.z + x2.w * w.w;
            acc3 += x3.x * w.x + x3.y * w.y + x3.z * w.z + x3.w * w.w;
        }
    }

    // row-major f16 Wx
    Wxf[(r0 + 0) * DOUT + o] = (_Float16)acc0;
    Wxf[(r0 + 1) * DOUT + o] = (_Float16)acc1;
    Wxf[(r0 + 2) * DOUT + o] = (_Float16)acc2;
    Wxf[(r0 + 3) * DOUT + o] = (_Float16)acc3;
    // transposed copy BT[o][node] for MFMA B-fragments (8B store, 4 nodes)
    {
        HU u0, u1;
        u0.h = h2{(_Float16)acc0, (_Float16)acc1};
        u1.h = h2{(_Float16)acc2, (_Float16)acc3};
        uint2 pv; pv.x = u0.u; pv.y = u1.u;
        *(uint2*)(BT + (size_t)o * NN + r0) = pv;
    }

    const int f = tid & 63;
    const int h = tid >> 6;
    if (blockIdx.x == 0) {
        if (tid == 0) *flagout = isbf;
        if (tid < 32) {
            HU p; p.h = h2{(_Float16)(0.4f * sa[2 * tid]),
                           (_Float16)(0.4f * sa[2 * tid + 1])};
            apk[tid] = p.u;
        }
    }

    const float af = 0.6f * sa[f];
    float v0 = af * acc0, v1 = af * acc1, v2 = af * acc2, v3 = af * acc3;
    #pragma unroll
    for (int d = 1; d < 64; d <<= 1) {
        v0 += __shfl_xor(v0, d);
        v1 += __shfl_xor(v1, d);
        v2 += __shfl_xor(v2, d);
        v3 += __shfl_xor(v3, d);
    }
    if (f == 0) {
        lin[(r0 + 0) * NH + h] = v0;
        lin[(r0 + 1) * NH + h] = v1;
        lin[(r0 + 2) * NH + h] = v2;
        lin[(r0 + 3) * NH + h] = v3;
    }
}

// ---------------------------------------------------------------------------
// K2 (fused): e + softmax + AV-MFMA. Block = (16 i-rows, 1 head); grid 48x4.
// e-phase:   wave wv covers j in [wv*192, wv*192+192) (3 steps of 64), lane=j.
//            wj (this lane's j head-slice, 8 x uint4) held in VGPRs; wi read
//            as wave-uniform 16B loads; v_pk_add_f16 + v_dot2_f32_f16 (f32
//            accumulate). e -> LDS f32 tile E[16][772] (masked -> -inf).
// softmax:   wave wv owns rows 4wv..4wv+3; max/exp/sum; P (f16) + S to LDS.
// AV:        out = P[16x768] . B[768x64] via v_mfma_f32_16x16x32_f16, B-frags
//            coalesced from BT. (MFMA path validated in round 5.)
// ---------------------------------------------------------------------------
#define EP 772   // 768 + 4 f32 pad
#define KP 776   // 768 + 8 f16 pad
__global__ __launch_bounds__(256) void gat_kernel(
    const _Float16* __restrict__ Wxf,
    const _Float16* __restrict__ BT,
    const float* __restrict__ lin,
    const unsigned int* __restrict__ apk,
    const int* __restrict__ adj,
    void* __restrict__ outv,
    const int* __restrict__ flag)
{
    __shared__ float E[16][EP];                 // 49408 B
    __shared__ __align__(16) _Float16 P[16][KP]; // 24832 B
    __shared__ float S[16];

    const int b    = blockIdx.x;
    const int h    = b & 3, it = b >> 2;
    const int i0   = it * 16;
    const int tid  = threadIdx.x;
    const int wv   = tid >> 6;
    const int lane = tid & 63;

    // 0.4*a packed, 8 x uint4 (wave-uniform)
    uint4 ap[8];
    #pragma unroll
    for (int c = 0; c < 8; ++c) ap[c] = *(const uint4*)(apk + c * 4);

    // ---- e-phase ----
    for (int s = 0; s < 3; ++s) {
        const int j = wv * 192 + s * 64 + lane;
        uint4 wj[8];
        #pragma unroll
        for (int c = 0; c < 8; ++c)
            wj[c] = *(const uint4*)(Wxf + (size_t)j * DOUT + h * FH + c * 8);
        const float linj = lin[j * NH + h];

        for (int r = 0; r < 16; ++r) {
            const int i = i0 + r;
            const int adjv = adj[(size_t)i * NN + j];
            const float lini = lin[i * NH + h];
            float acc = 0.f;
            #pragma unroll
            for (int c = 0; c < 8; ++c) {
                const uint4 wiv = *(const uint4*)(Wxf + (size_t)i * DOUT + h * FH + c * 8);
                acc = dot2abs(ap[c].x, pkadd(wiv.x, wj[c].x), acc);
                acc = dot2abs(ap[c].y, pkadd(wiv.y, wj[c].y), acc);
                acc = dot2abs(ap[c].z, pkadd(wiv.z, wj[c].z), acc);
                acc = dot2abs(ap[c].w, pkadd(wiv.w, wj[c].w), acc);
            }
            E[r][j] = adjv ? (acc + lini + linj) : -__builtin_inff();
        }
    }
    __syncthreads();

    // ---- softmax: wave wv owns rows 4wv..4wv+3 ----
    #pragma unroll
    for (int rr = 0; rr < 4; ++rr) {
        const int row = wv * 4 + rr;
        float v[12];
        float m = -__builtin_inff();
        #pragma unroll
        for (int c = 0; c < 12; ++c) {
            v[c] = E[row][c * 64 + lane];
            m = fmaxf(m, v[c]);
        }
        #pragma unroll
        for (int d = 1; d < 64; d <<= 1) m = fmaxf(m, __shfl_xor(m, d));
        if (m == -__builtin_inff()) m = 0.f;   // all-masked row: exps -> 0, not NaN
        float sum = 0.f;
        #pragma unroll
        for (int c = 0; c < 12; ++c) {
            const float ev = __expf(v[c] - m);   // masked (-inf) -> 0
            sum += ev;
            P[row][c * 64 + lane] = (_Float16)ev;
        }
        #pragma unroll
        for (int d = 1; d < 64; d <<= 1) sum += __shfl_xor(sum, d);
        if (lane == 0) S[row] = fmaxf(sum, 1e-30f);
    }
    __syncthreads();

    // ---- MFMA AV ----
    const int mrow = lane & 15;
    const int quad = lane >> 4;
    const int n0   = wv * 16;
    f4 acc = {0.f, 0.f, 0.f, 0.f};
    const _Float16* bbase = BT + ((size_t)(h * FH + n0 + mrow)) * NN + quad * 8;
    const _Float16* abase = &P[mrow][quad * 8];
    #pragma unroll 4
    for (int k0 = 0; k0 < NN; k0 += 32) {
        const h8 af = *(const h8*)(abase + k0);
        const h8 bf = *(const h8*)(bbase + k0);
        acc = __builtin_amdgcn_mfma_f32_16x16x32_f16(af, bf, acc, 0, 0, 0);
    }

    // ---- normalize + store (C layout: col=lane&15, row=quad*4+r) ----
    const int isbf = *flag;
    #pragma unroll
    for (int r = 0; r < 4; ++r) {
        const int row = quad * 4 + r;
        const float val = acc[r] / S[row];
        const size_t oidx = (size_t)(i0 + row) * DOUT + h * FH + n0 + mrow;
        if (isbf) ((unsigned short*)outv)[oidx] = f2b(val);
        else      ((float*)outv)[oidx] = val;
    }
}

extern "C" void kernel_launch(void* const* d_in, const int* in_sizes, int n_in,
                              void* d_out, int out_size, void* d_ws, size_t ws_size,
                              hipStream_t stream) {
    const void* px = d_in[0]; const void* padj = d_in[1];
    const void* pW = d_in[2]; const void* pa  = d_in[3];
    for (int t = 0; t < n_in; ++t) {
        switch (in_sizes[t]) {
            case NN * INP:   px   = d_in[t]; break;   // 196608
            case NN * NN:    padj = d_in[t]; break;   // 589824
            case DOUT * INP: pW   = d_in[t]; break;   // 65536
            case FH:         pa   = d_in[t]; break;   // 64
        }
    }

    char* ws = (char*)d_ws;
    int*          flag = (int*)ws;                         // [0,256)
    unsigned int* apk  = (unsigned int*)(ws + 256);        // 128 B
    float*        lin  = (float*)(ws + 1024);              // 12288 B -> ends 13312
    _Float16*     Wxf  = (_Float16*)(ws + 16384);          // 393216 B -> ends 409600
    _Float16*     BT   = (_Float16*)(ws + 409600);         // 393216 B -> ends 802816

    wx_kernel<<<NN / 4, 256, 0, stream>>>(px, pW, pa, Wxf, BT, lin, apk, flag);
    gat_kernel<<<(NN / 16) * NH, 256, 0, stream>>>(Wxf, BT, lin, apk,
                                                   (const int*)padj, d_out, flag);
}